// Round 10
// baseline (736.743 us; speedup 1.0000x reference)
//
#include <hip/hip_runtime.h>
#include <hip/hip_cooperative_groups.h>
#include <math.h>
#include <float.h>

namespace cg = cooperative_groups;

#define BGRAPH 16
#define NPTS   2048
#define CDIM   16
#define ODIM   64
#define KNN    16
#define NTOT   (BGRAPH*NPTS)     // 32768
#define NEDGE  (NTOT*KNN)        // 524288
#define EPSBN  1e-5f
#define NBLK_E 2048              // blocks for fallback edge-stat passes
#define NBLKF  1024              // blocks for fused cooperative kernel
#define NPW    4                 // nodes per wave in fallback edge-stat passes

// ---------------- P = x@W1b, Q = x@(W1a-W1b)+b1, sq = rowsum(x*x) ----------
__global__ __launch_bounds__(256) void pq_kernel(
    const float* __restrict__ x, const float* __restrict__ W1,
    const float* __restrict__ b1,
    float* __restrict__ P, float* __restrict__ Q, float* __restrict__ sq) {
  int lane = threadIdx.x & 63;
  int nin  = threadIdx.x >> 6;           // node within block (0..3)
  int node = blockIdx.x * 4 + nin;
  __shared__ float xs[4][CDIM];
  if (threadIdx.x < 4*CDIM) {
    int n = threadIdx.x / CDIM, c = threadIdx.x % CDIM;
    xs[n][c] = x[(blockIdx.x*4 + n)*CDIM + c];
  }
  __syncthreads();
  float p = 0.f, q = b1[lane];
  #pragma unroll
  for (int c = 0; c < CDIM; ++c) {
    float xv = xs[nin][c];
    float wb = W1[(c+CDIM)*ODIM + lane];
    float wa = W1[c*ODIM + lane];
    p += xv * wb;
    q += xv * (wa - wb);
  }
  P[node*ODIM + lane] = p;
  Q[node*ODIM + lane] = q;
  if (lane == 0) {
    float s = 0.f;
    #pragma unroll
    for (int c = 0; c < CDIM; ++c) { float xv = xs[nin][c]; s += xv*xv; }
    sq[node] = s;
  }
}

// ---------------- kNN: one row per wave, all state in registers -------------
// FROZEN round-1 kernel (measured r6/r9: ~114us, VGPR=60, WRITE=2MB). Every
// R=2 attempt (r2-r5) put the distance array in scratch (2GB WRITE, 7-11x
// slower). Flat d[32] + ~56 VGPR demand is the proven-promotable shape on
// this compiler. Do not increase per-thread state here.
#define KROWS 4
__device__ __forceinline__ unsigned long long packkey(float dv, int j) {
  unsigned ub = __float_as_uint(dv);
  ub ^= ((unsigned)((int)ub >> 31)) | 0x80000000u;   // monotone f32->u32
  return (((unsigned long long)ub) << 32) | (unsigned)j;
}

__global__ __launch_bounds__(256, 4) void knn_kernel(
    const float* __restrict__ x, const float* __restrict__ sq,
    int* __restrict__ idxOut) {
  __shared__ float sT16[CDIM][256];                 // transposed tile, 16 KB
  __shared__ unsigned long long skey[4][64];        // per-wave survivor keys
  __shared__ int scnt[4];
  const int tid  = threadIdx.x;
  const int lane = tid & 63;
  const int w    = tid >> 6;
  const int blocksPerGraph = NPTS / KROWS;          // 512
  const int g     = blockIdx.x / blocksPerGraph;
  const int rb    = (blockIdx.x % blocksPerGraph) * KROWS;
  const int gbase = g * NPTS;
  const int r0    = rb + w;                         // this wave's single row

  float tg[CDIM]; float tsq;
  {
    const float4* tp = (const float4*)(x + (size_t)(gbase + r0)*CDIM);
    float4 t0 = tp[0], t1 = tp[1], t2 = tp[2], t3 = tp[3];
    tg[0]=t0.x; tg[1]=t0.y; tg[2]=t0.z; tg[3]=t0.w;
    tg[4]=t1.x; tg[5]=t1.y; tg[6]=t1.z; tg[7]=t1.w;
    tg[8]=t2.x; tg[9]=t2.y; tg[10]=t2.z; tg[11]=t2.w;
    tg[12]=t3.x; tg[13]=t3.y; tg[14]=t3.z; tg[15]=t3.w;
    tsq = sq[gbase + r0];
  }

  float d[32];

  // prefetch tile 0 into regs
  float4 a0, a1, a2, a3;
  {
    const float4* xp = (const float4*)(x + (size_t)(gbase + tid)*CDIM);
    a0 = xp[0]; a1 = xp[1]; a2 = xp[2]; a3 = xp[3];
  }

  for (int t = 0; t < NPTS/256; ++t) {
    __syncthreads();                                // prev tile reads done
    sT16[0][tid]=a0.x;  sT16[1][tid]=a0.y;  sT16[2][tid]=a0.z;  sT16[3][tid]=a0.w;
    sT16[4][tid]=a1.x;  sT16[5][tid]=a1.y;  sT16[6][tid]=a1.z;  sT16[7][tid]=a1.w;
    sT16[8][tid]=a2.x;  sT16[9][tid]=a2.y;  sT16[10][tid]=a2.z; sT16[11][tid]=a2.w;
    sT16[12][tid]=a3.x; sT16[13][tid]=a3.y; sT16[14][tid]=a3.z; sT16[15][tid]=a3.w;
    __syncthreads();
    if (t < NPTS/256 - 1) {                         // issue next-tile loads early
      const float4* xp = (const float4*)(x + (size_t)(gbase + (t+1)*256 + tid)*CDIM);
      a0 = xp[0]; a1 = xp[1]; a2 = xp[2]; a3 = xp[3];
    }

    float4 sq4 = *(const float4*)(sq + gbase + t*256 + 4*lane);
    float sqv[4] = {sq4.x, sq4.y, sq4.z, sq4.w};

    float dot[4] = {0.f,0.f,0.f,0.f};
    #pragma unroll
    for (int c = 0; c < CDIM; ++c) {
      float4 cv = *(const float4*)(&sT16[c][4*lane]);
      float cvv[4]; cvv[0]=cv.x; cvv[1]=cv.y; cvv[2]=cv.z; cvv[3]=cv.w;
      float xv = tg[c];
      #pragma unroll
      for (int rr = 0; rr < 4; ++rr)
        dot[rr] += xv * cvv[rr];
    }
    #pragma unroll
    for (int rr = 0; rr < 4; ++rr)
      d[t*4 + rr] = tsq + sqv[rr] - 2.f*dot[rr];
  }

  {
    float lmin = d[0];
    #pragma unroll
    for (int s = 1; s < 32; ++s) lmin = fminf(lmin, d[s]);

    float v = lmin;
    #pragma unroll
    for (int k = 2; k <= 64; k <<= 1) {
      #pragma unroll
      for (int j = k >> 1; j > 0; j >>= 1) {
        float o = __shfl_xor(v, j);
        bool asc   = ((lane & k) == 0);
        bool lower = ((lane & j) == 0);
        float mn = fminf(v, o), mx = fmaxf(v, o);
        v = (asc == lower) ? mn : mx;
      }
    }
    float T = __shfl(v, 15);

    if (lane == 0) scnt[w] = 0;
    #pragma unroll
    for (int s = 0; s < 32; ++s) {
      if (d[s] <= T) {
        int p = atomicAdd(&scnt[w], 1);
        if (p < 64) {
          int j = (s >> 2)*256 + 4*lane + (s & 3);
          skey[w][p] = packkey(d[s], j);
        }
      }
    }
    int M = scnt[w];
    int row = gbase + r0;

    if (M <= 64) {
      unsigned long long key = (lane < M) ? skey[w][lane] : ~0ull;
      #pragma unroll
      for (int k = 2; k <= 64; k <<= 1) {
        #pragma unroll
        for (int j = k >> 1; j > 0; j >>= 1) {
          unsigned long long o = __shfl_xor(key, j);
          bool asc   = ((lane & k) == 0);
          bool lower = ((lane & j) == 0);
          unsigned long long mn = (key < o) ? key : o;
          unsigned long long mx = (key < o) ? o : key;
          key = (asc == lower) ? mn : mx;
        }
      }
      if (lane < KNN)
        idxOut[(size_t)row*KNN + lane] = gbase + (int)(key & 0xffffffffu);
    } else {
      for (int sel = 0; sel < KNN; ++sel) {
        unsigned long long lb = ~0ull;
        #pragma unroll
        for (int s = 0; s < 32; ++s) {
          int j = (s >> 2)*256 + 4*lane + (s & 3);
          unsigned long long ks = packkey(d[s], j);
          if (ks < lb) lb = ks;
        }
        #pragma unroll
        for (int off = 32; off > 0; off >>= 1) {
          unsigned long long o = __shfl_xor(lb, off);
          if (o < lb) lb = o;
        }
        if (lane == 0)
          idxOut[(size_t)row*KNN + sel] = gbase + (int)(lb & 0xffffffffu);
        #pragma unroll
        for (int s = 0; s < 32; ++s) {
          int j = (s >> 2)*256 + 4*lane + (s & 3);
          if (packkey(d[s], j) == lb) d[s] = FLT_MAX;
        }
      }
    }
  }
}

// ============ FUSED cooperative kernel: stats1+fin1+stats2+fin2+final =======
// Tail is ~60us of launch-gap overhead (r9 accounting: 165us tail vs ~100us
// computed work). One cooperative kernel, 5 phases, grid.sync() between.
// 1024 blocks x 256 thr, launch_bounds(256,4) -> VGPR<=128, 4 blocks/CU
// guaranteed co-resident (1024 = 4*256). Block owns 32 nodes; wave owns 8.
// Phase bodies are the r9-verified grouped kernels with NBLK 2048->1024.
__global__ __launch_bounds__(256, 4) void fused_kernel(
    const float* __restrict__ P, const float* __restrict__ Q,
    const int* __restrict__ idx,
    const float* __restrict__ g1, const float* __restrict__ be1,
    const float* __restrict__ Wg, const float* __restrict__ bg,
    const float* __restrict__ gg, const float* __restrict__ beg,
    float* __restrict__ pbuf, float* __restrict__ gpart,
    float* __restrict__ gtbuf, float* __restrict__ scale,
    float* __restrict__ shift, float* __restrict__ gsc,
    float* __restrict__ out) {
  cg::grid_group grid = cg::this_grid();
  const int tid  = threadIdx.x;
  const int lane = tid & 63;
  const int wid  = tid >> 6;
  const int grp  = lane >> 4;           // edge-quad slot 0..3
  const int p    = lane & 15;           // channel quad 0..15
  const int blk  = blockIdx.x;
  const int nw0  = blk*32 + wid*8;      // this wave's 8 nodes

  __shared__ float ls[4][ODIM], lss[4][ODIM];
  __shared__ float ra[256], rb[256];
  __shared__ float pw[4], pws[4];

  // ---------- Phase A: edge-stat pass 1 (per-channel sum/sumsq of h) -------
  {
    float4 s4 = {0.f,0.f,0.f,0.f};
    float4 ss4 = {0.f,0.f,0.f,0.f};
    for (int ii = 0; ii < 8; ++ii) {
      int i = nw0 + ii;
      float4 q4 = *(const float4*)(Q + (size_t)i*ODIM + 4*p);
      int4 j4 = *(const int4*)(idx + (size_t)i*KNN + 4*grp);
      {
        float4 v = *(const float4*)(P + (size_t)j4.x*ODIM + 4*p);
        float hx=q4.x+v.x, hy=q4.y+v.y, hz=q4.z+v.z, hw=q4.w+v.w;
        s4.x+=hx; s4.y+=hy; s4.z+=hz; s4.w+=hw;
        ss4.x+=hx*hx; ss4.y+=hy*hy; ss4.z+=hz*hz; ss4.w+=hw*hw;
      }
      {
        float4 v = *(const float4*)(P + (size_t)j4.y*ODIM + 4*p);
        float hx=q4.x+v.x, hy=q4.y+v.y, hz=q4.z+v.z, hw=q4.w+v.w;
        s4.x+=hx; s4.y+=hy; s4.z+=hz; s4.w+=hw;
        ss4.x+=hx*hx; ss4.y+=hy*hy; ss4.z+=hz*hz; ss4.w+=hw*hw;
      }
      {
        float4 v = *(const float4*)(P + (size_t)j4.z*ODIM + 4*p);
        float hx=q4.x+v.x, hy=q4.y+v.y, hz=q4.z+v.z, hw=q4.w+v.w;
        s4.x+=hx; s4.y+=hy; s4.z+=hz; s4.w+=hw;
        ss4.x+=hx*hx; ss4.y+=hy*hy; ss4.z+=hz*hz; ss4.w+=hw*hw;
      }
      {
        float4 v = *(const float4*)(P + (size_t)j4.w*ODIM + 4*p);
        float hx=q4.x+v.x, hy=q4.y+v.y, hz=q4.z+v.z, hw=q4.w+v.w;
        s4.x+=hx; s4.y+=hy; s4.z+=hz; s4.w+=hw;
        ss4.x+=hx*hx; ss4.y+=hy*hy; ss4.z+=hz*hz; ss4.w+=hw*hw;
      }
    }
    s4.x  += __shfl_xor(s4.x,16);  s4.x  += __shfl_xor(s4.x,32);
    s4.y  += __shfl_xor(s4.y,16);  s4.y  += __shfl_xor(s4.y,32);
    s4.z  += __shfl_xor(s4.z,16);  s4.z  += __shfl_xor(s4.z,32);
    s4.w  += __shfl_xor(s4.w,16);  s4.w  += __shfl_xor(s4.w,32);
    ss4.x += __shfl_xor(ss4.x,16); ss4.x += __shfl_xor(ss4.x,32);
    ss4.y += __shfl_xor(ss4.y,16); ss4.y += __shfl_xor(ss4.y,32);
    ss4.z += __shfl_xor(ss4.z,16); ss4.z += __shfl_xor(ss4.z,32);
    ss4.w += __shfl_xor(ss4.w,16); ss4.w += __shfl_xor(ss4.w,32);
    if (grp == 0) {
      *(float4*)&ls[wid][4*p]  = s4;
      *(float4*)&lss[wid][4*p] = ss4;
    }
    __syncthreads();
    if (tid < ODIM) {
      pbuf[(size_t)tid*NBLKF + blk] = ls[0][tid]+ls[1][tid]+ls[2][tid]+ls[3][tid];
    } else if (tid < 2*ODIM) {
      int o = tid - ODIM;
      pbuf[(size_t)(ODIM+o)*NBLKF + blk] = lss[0][o]+lss[1][o]+lss[2][o]+lss[3][o];
    }
  }
  grid.sync();

  // ---------- Phase B: fin1 on blocks 0..63 (channel o = blk) --------------
  if (blk < ODIM) {
    int o = blk;
    float s = 0.f, ss = 0.f;
    for (int t = tid; t < NBLKF; t += 256) {
      s  += pbuf[(size_t)o*NBLKF + t];
      ss += pbuf[(size_t)(ODIM+o)*NBLKF + t];
    }
    ra[tid] = s; rb[tid] = ss;
    __syncthreads();
    #pragma unroll
    for (int st = 128; st > 0; st >>= 1) {
      if (tid < st) { ra[tid] += ra[tid+st]; rb[tid] += rb[tid+st]; }
      __syncthreads();
    }
    if (tid == 0) {
      float mu  = ra[0] / (float)NEDGE;
      float var = rb[0] / (float)NEDGE - mu*mu;
      float inv = 1.0f / sqrtf(var + EPSBN);
      float sc = g1[o] * inv;
      scale[o] = sc;
      shift[o] = be1[o] - mu * sc;
    }
  }
  grid.sync();

  // ---------- Phase C: gate pass (stats2) ----------------------------------
  {
    float4 sc4 = *(const float4*)(scale + 4*p);
    float4 sh4 = *(const float4*)(shift + 4*p);
    float4 wg4 = *(const float4*)(Wg + 4*p);
    float bgv = bg[0];
    float s = 0.f, ss = 0.f;
    for (int ii = 0; ii < 8; ++ii) {
      int i = nw0 + ii;
      float4 q4 = *(const float4*)(Q + (size_t)i*ODIM + 4*p);
      int4 j4 = *(const int4*)(idx + (size_t)i*KNN + 4*grp);
      #pragma unroll
      for (int e = 0; e < 4; ++e) {
        int j = (e==0) ? j4.x : (e==1) ? j4.y : (e==2) ? j4.z : j4.w;
        float4 p4 = *(const float4*)(P + (size_t)j*ODIM + 4*p);
        float zx = (q4.x + p4.x)*sc4.x + sh4.x;
        float zy = (q4.y + p4.y)*sc4.y + sh4.y;
        float zz = (q4.z + p4.z)*sc4.z + sh4.z;
        float zw = (q4.w + p4.w)*sc4.w + sh4.w;
        float v = (zx/(1.f+expf(-zx)))*wg4.x
                + (zy/(1.f+expf(-zy)))*wg4.y
                + (zz/(1.f+expf(-zz)))*wg4.z
                + (zw/(1.f+expf(-zw)))*wg4.w;
        v += __shfl_xor(v, 1);
        v += __shfl_xor(v, 2);
        v += __shfl_xor(v, 4);
        v += __shfl_xor(v, 8);          // group-wide sum over 64 channels
        float gt = v + bgv;
        if (p == 0) gtbuf[(size_t)i*KNN + 4*grp + e] = gt;
        s += gt; ss += gt*gt;
      }
    }
    // each group's total enters exactly once (xor16/32 cross groups only)
    s  += __shfl_xor(s, 16);  s  += __shfl_xor(s, 32);
    ss += __shfl_xor(ss, 16); ss += __shfl_xor(ss, 32);
    if (lane == 0) { pw[wid] = s; pws[wid] = ss; }
    __syncthreads();
    if (tid == 0) {
      gpart[2*blk]   = pw[0]+pw[1]+pw[2]+pw[3];
      gpart[2*blk+1] = pws[0]+pws[1]+pws[2]+pws[3];
    }
  }
  grid.sync();

  // ---------- Phase D: fin2 on block 0 -------------------------------------
  if (blk == 0) {
    float s = 0.f, ss = 0.f;
    for (int t = tid; t < NBLKF; t += 256) { s += gpart[2*t]; ss += gpart[2*t+1]; }
    __syncthreads();
    ra[tid] = s; rb[tid] = ss;
    __syncthreads();
    #pragma unroll
    for (int st = 128; st > 0; st >>= 1) {
      if (tid < st) { ra[tid] += ra[tid+st]; rb[tid] += rb[tid+st]; }
      __syncthreads();
    }
    if (tid == 0) {
      float mu  = ra[0] / (float)NEDGE;
      float var = rb[0] / (float)NEDGE - mu*mu;
      float inv = 1.f / sqrtf(var + EPSBN);
      float sg = gg[0] * inv;
      gsc[0] = sg; gsc[1] = beg[0] - mu * sg;
    }
  }
  grid.sync();

  // ---------- Phase E: final (softmax over K + weighted sum) ---------------
  {
    float4 sc4 = *(const float4*)(scale + 4*p);
    float4 sh4 = *(const float4*)(shift + 4*p);
    float gscale = gsc[0], gshift = gsc[1];
    for (int ii = 0; ii < 8; ++ii) {
      int i = nw0 + ii;
      float4 q4 = *(const float4*)(Q + (size_t)i*ODIM + 4*p);
      int4   j4 = *(const int4*)(idx + (size_t)i*KNN + 4*grp);
      float4 g4 = *(const float4*)(gtbuf + (size_t)i*KNN + 4*grp);

      float z0 = g4.x*gscale + gshift, z1 = g4.y*gscale + gshift;
      float z2 = g4.z*gscale + gshift, z3 = g4.w*gscale + gshift;
      float gt0 = z0/(1.f+expf(-z0)), gt1 = z1/(1.f+expf(-z1));
      float gt2 = z2/(1.f+expf(-z2)), gt3 = z3/(1.f+expf(-z3));
      float m = fmaxf(fmaxf(gt0, gt1), fmaxf(gt2, gt3));
      m = fmaxf(m, __shfl_xor(m, 16));
      m = fmaxf(m, __shfl_xor(m, 32));
      float e0 = expf(gt0-m), e1 = expf(gt1-m), e2 = expf(gt2-m), e3 = expf(gt3-m);
      float se = e0+e1+e2+e3;
      se += __shfl_xor(se, 16);
      se += __shfl_xor(se, 32);
      float invs = 1.f / se;
      float a0 = e0*invs, a1 = e1*invs, a2 = e2*invs, a3 = e3*invs;

      float4 acc = {0.f,0.f,0.f,0.f};
      {
        float4 v = *(const float4*)(P + (size_t)j4.x*ODIM + 4*p);
        float zx=(q4.x+v.x)*sc4.x+sh4.x, zy=(q4.y+v.y)*sc4.y+sh4.y;
        float zz=(q4.z+v.z)*sc4.z+sh4.z, zw=(q4.w+v.w)*sc4.w+sh4.w;
        acc.x += a0*(zx/(1.f+expf(-zx))); acc.y += a0*(zy/(1.f+expf(-zy)));
        acc.z += a0*(zz/(1.f+expf(-zz))); acc.w += a0*(zw/(1.f+expf(-zw)));
      }
      {
        float4 v = *(const float4*)(P + (size_t)j4.y*ODIM + 4*p);
        float zx=(q4.x+v.x)*sc4.x+sh4.x, zy=(q4.y+v.y)*sc4.y+sh4.y;
        float zz=(q4.z+v.z)*sc4.z+sh4.z, zw=(q4.w+v.w)*sc4.w+sh4.w;
        acc.x += a1*(zx/(1.f+expf(-zx))); acc.y += a1*(zy/(1.f+expf(-zy)));
        acc.z += a1*(zz/(1.f+expf(-zz))); acc.w += a1*(zw/(1.f+expf(-zw)));
      }
      {
        float4 v = *(const float4*)(P + (size_t)j4.z*ODIM + 4*p);
        float zx=(q4.x+v.x)*sc4.x+sh4.x, zy=(q4.y+v.y)*sc4.y+sh4.y;
        float zz=(q4.z+v.z)*sc4.z+sh4.z, zw=(q4.w+v.w)*sc4.w+sh4.w;
        acc.x += a2*(zx/(1.f+expf(-zx))); acc.y += a2*(zy/(1.f+expf(-zy)));
        acc.z += a2*(zz/(1.f+expf(-zz))); acc.w += a2*(zw/(1.f+expf(-zw)));
      }
      {
        float4 v = *(const float4*)(P + (size_t)j4.w*ODIM + 4*p);
        float zx=(q4.x+v.x)*sc4.x+sh4.x, zy=(q4.y+v.y)*sc4.y+sh4.y;
        float zz=(q4.z+v.z)*sc4.z+sh4.z, zw=(q4.w+v.w)*sc4.w+sh4.w;
        acc.x += a3*(zx/(1.f+expf(-zx))); acc.y += a3*(zy/(1.f+expf(-zy)));
        acc.z += a3*(zz/(1.f+expf(-zz))); acc.w += a3*(zw/(1.f+expf(-zw)));
      }
      acc.x += __shfl_xor(acc.x,16); acc.x += __shfl_xor(acc.x,32);
      acc.y += __shfl_xor(acc.y,16); acc.y += __shfl_xor(acc.y,32);
      acc.z += __shfl_xor(acc.z,16); acc.z += __shfl_xor(acc.z,32);
      acc.w += __shfl_xor(acc.w,16); acc.w += __shfl_xor(acc.w,32);
      if (grp == 0)
        *(float4*)(out + (size_t)i*ODIM + 4*p) = acc;
    }
  }
}

// ================= fallback standalone kernels (r9-verified) ================
__global__ __launch_bounds__(256) void stats1_kernel(
    const float* __restrict__ P, const float* __restrict__ Q,
    const int* __restrict__ idx, float* __restrict__ pbuf) {
  int lane = threadIdx.x & 63;
  int wid  = threadIdx.x >> 6;
  int grp  = lane >> 4;
  int p    = lane & 15;
  int gw   = blockIdx.x * 4 + wid;
  int n0 = gw * NPW;
  float4 s4  = {0.f,0.f,0.f,0.f};
  float4 ss4 = {0.f,0.f,0.f,0.f};
  #pragma unroll
  for (int ii = 0; ii < NPW; ++ii) {
    int i = n0 + ii;
    float4 q4 = *(const float4*)(Q + (size_t)i*ODIM + 4*p);
    int4 j4 = *(const int4*)(idx + (size_t)i*KNN + 4*grp);
    {
      float4 v = *(const float4*)(P + (size_t)j4.x*ODIM + 4*p);
      float hx=q4.x+v.x, hy=q4.y+v.y, hz=q4.z+v.z, hw=q4.w+v.w;
      s4.x+=hx; s4.y+=hy; s4.z+=hz; s4.w+=hw;
      ss4.x+=hx*hx; ss4.y+=hy*hy; ss4.z+=hz*hz; ss4.w+=hw*hw;
    }
    {
      float4 v = *(const float4*)(P + (size_t)j4.y*ODIM + 4*p);
      float hx=q4.x+v.x, hy=q4.y+v.y, hz=q4.z+v.z, hw=q4.w+v.w;
      s4.x+=hx; s4.y+=hy; s4.z+=hz; s4.w+=hw;
      ss4.x+=hx*hx; ss4.y+=hy*hy; ss4.z+=hz*hz; ss4.w+=hw*hw;
    }
    {
      float4 v = *(const float4*)(P + (size_t)j4.z*ODIM + 4*p);
      float hx=q4.x+v.x, hy=q4.y+v.y, hz=q4.z+v.z, hw=q4.w+v.w;
      s4.x+=hx; s4.y+=hy; s4.z+=hz; s4.w+=hw;
      ss4.x+=hx*hx; ss4.y+=hy*hy; ss4.z+=hz*hz; ss4.w+=hw*hw;
    }
    {
      float4 v = *(const float4*)(P + (size_t)j4.w*ODIM + 4*p);
      float hx=q4.x+v.x, hy=q4.y+v.y, hz=q4.z+v.z, hw=q4.w+v.w;
      s4.x+=hx; s4.y+=hy; s4.z+=hz; s4.w+=hw;
      ss4.x+=hx*hx; ss4.y+=hy*hy; ss4.z+=hz*hz; ss4.w+=hw*hw;
    }
  }
  s4.x  += __shfl_xor(s4.x,16);  s4.x  += __shfl_xor(s4.x,32);
  s4.y  += __shfl_xor(s4.y,16);  s4.y  += __shfl_xor(s4.y,32);
  s4.z  += __shfl_xor(s4.z,16);  s4.z  += __shfl_xor(s4.z,32);
  s4.w  += __shfl_xor(s4.w,16);  s4.w  += __shfl_xor(s4.w,32);
  ss4.x += __shfl_xor(ss4.x,16); ss4.x += __shfl_xor(ss4.x,32);
  ss4.y += __shfl_xor(ss4.y,16); ss4.y += __shfl_xor(ss4.y,32);
  ss4.z += __shfl_xor(ss4.z,16); ss4.z += __shfl_xor(ss4.z,32);
  ss4.w += __shfl_xor(ss4.w,16); ss4.w += __shfl_xor(ss4.w,32);
  __shared__ float ls[4][ODIM], lss[4][ODIM];
  if (grp == 0) {
    *(float4*)&ls[wid][4*p]  = s4;
    *(float4*)&lss[wid][4*p] = ss4;
  }
  __syncthreads();
  int tid = threadIdx.x;
  if (tid < ODIM) {
    float a = ls[0][tid] + ls[1][tid] + ls[2][tid] + ls[3][tid];
    pbuf[(size_t)tid*NBLK_E + blockIdx.x] = a;
  } else if (tid < 2*ODIM) {
    int o = tid - ODIM;
    float a = lss[0][o] + lss[1][o] + lss[2][o] + lss[3][o];
    pbuf[(size_t)(ODIM+o)*NBLK_E + blockIdx.x] = a;
  }
}

__global__ __launch_bounds__(64) void fin1_kernel(
    const float* __restrict__ pbuf,
    const float* __restrict__ g1, const float* __restrict__ be1,
    float* __restrict__ scale, float* __restrict__ shift) {
  int o = blockIdx.x, lane = threadIdx.x;
  const float* ps = pbuf + (size_t)o*NBLK_E;
  const float* pq = pbuf + (size_t)(ODIM+o)*NBLK_E;
  float s = 0.f, ss = 0.f;
  for (int t = lane; t < NBLK_E; t += 64) { s += ps[t]; ss += pq[t]; }
  #pragma unroll
  for (int off = 32; off > 0; off >>= 1) {
    s  += __shfl_xor(s, off);
    ss += __shfl_xor(ss, off);
  }
  if (lane == 0) {
    float mu  = s / (float)NEDGE;
    float var = ss / (float)NEDGE - mu*mu;
    float inv = 1.0f / sqrtf(var + EPSBN);
    float sc = g1[o] * inv;
    scale[o] = sc;
    shift[o] = be1[o] - mu * sc;
  }
}

__global__ __launch_bounds__(256) void stats2_kernel(
    const float* __restrict__ P, const float* __restrict__ Q,
    const int* __restrict__ idx, const float* __restrict__ scale,
    const float* __restrict__ shift, const float* __restrict__ Wg,
    const float* __restrict__ bg, float* __restrict__ gtbuf,
    float* __restrict__ gpart) {
  int lane = threadIdx.x & 63;
  int wid  = threadIdx.x >> 6;
  int grp  = lane >> 4;
  int p    = lane & 15;
  int gw   = blockIdx.x * 4 + wid;
  int n0 = gw * NPW;
  float4 sc4 = *(const float4*)(scale + 4*p);
  float4 sh4 = *(const float4*)(shift + 4*p);
  float4 wg4 = *(const float4*)(Wg + 4*p);
  float bgv = bg[0];
  float s = 0.f, ss = 0.f;
  #pragma unroll
  for (int ii = 0; ii < NPW; ++ii) {
    int i = n0 + ii;
    float4 q4 = *(const float4*)(Q + (size_t)i*ODIM + 4*p);
    int4 j4 = *(const int4*)(idx + (size_t)i*KNN + 4*grp);
    #pragma unroll
    for (int e = 0; e < 4; ++e) {
      int j = (e==0) ? j4.x : (e==1) ? j4.y : (e==2) ? j4.z : j4.w;
      float4 p4 = *(const float4*)(P + (size_t)j*ODIM + 4*p);
      float zx = (q4.x + p4.x)*sc4.x + sh4.x;
      float zy = (q4.y + p4.y)*sc4.y + sh4.y;
      float zz = (q4.z + p4.z)*sc4.z + sh4.z;
      float zw = (q4.w + p4.w)*sc4.w + sh4.w;
      float v = (zx/(1.f+expf(-zx)))*wg4.x
              + (zy/(1.f+expf(-zy)))*wg4.y
              + (zz/(1.f+expf(-zz)))*wg4.z
              + (zw/(1.f+expf(-zw)))*wg4.w;
      v += __shfl_xor(v, 1);
      v += __shfl_xor(v, 2);
      v += __shfl_xor(v, 4);
      v += __shfl_xor(v, 8);
      float gt = v + bgv;
      if (p == 0) gtbuf[(size_t)i*KNN + 4*grp + e] = gt;
      s += gt; ss += gt*gt;
    }
  }
  s  += __shfl_xor(s, 16);  s  += __shfl_xor(s, 32);
  ss += __shfl_xor(ss, 16); ss += __shfl_xor(ss, 32);
  __shared__ float pw[4], pws[4];
  if (lane == 0) { pw[wid] = s; pws[wid] = ss; }
  __syncthreads();
  if (threadIdx.x == 0) {
    gpart[2*blockIdx.x]   = pw[0]+pw[1]+pw[2]+pw[3];
    gpart[2*blockIdx.x+1] = pws[0]+pws[1]+pws[2]+pws[3];
  }
}

__global__ __launch_bounds__(256) void fin2_kernel(
    const float* __restrict__ gpart,
    const float* __restrict__ gg, const float* __restrict__ beg,
    float* __restrict__ gsc) {
  int tid = threadIdx.x;
  float s = 0.f, ss = 0.f;
  for (int t = tid; t < NBLK_E; t += 256) { s += gpart[2*t]; ss += gpart[2*t+1]; }
  __shared__ float as[256], bs[256];
  as[tid] = s; bs[tid] = ss;
  __syncthreads();
  #pragma unroll
  for (int st = 128; st > 0; st >>= 1) {
    if (tid < st) { as[tid] += as[tid+st]; bs[tid] += bs[tid+st]; }
    __syncthreads();
  }
  if (tid == 0) {
    float mu  = as[0] / (float)NEDGE;
    float var = bs[0] / (float)NEDGE - mu*mu;
    float inv = 1.f / sqrtf(var + EPSBN);
    float sg = gg[0] * inv;
    gsc[0] = sg; gsc[1] = beg[0] - mu * sg;
  }
}

__global__ __launch_bounds__(256) void final_kernel(
    const float* __restrict__ P, const float* __restrict__ Q,
    const int* __restrict__ idx, const float* __restrict__ scale,
    const float* __restrict__ shift, const float* __restrict__ gtbuf,
    const float* __restrict__ gsc, float* __restrict__ out) {
  int lane = threadIdx.x & 63;
  int wid  = threadIdx.x >> 6;
  int grp  = lane >> 4;
  int p    = lane & 15;
  int i = blockIdx.x * 4 + wid;
  float4 sc4 = *(const float4*)(scale + 4*p);
  float4 sh4 = *(const float4*)(shift + 4*p);
  float gscale = gsc[0], gshift = gsc[1];
  float4 q4 = *(const float4*)(Q + (size_t)i*ODIM + 4*p);
  int4   j4 = *(const int4*)(idx + (size_t)i*KNN + 4*grp);
  float4 g4 = *(const float4*)(gtbuf + (size_t)i*KNN + 4*grp);

  float z0 = g4.x*gscale + gshift, z1 = g4.y*gscale + gshift;
  float z2 = g4.z*gscale + gshift, z3 = g4.w*gscale + gshift;
  float gt0 = z0/(1.f+expf(-z0)), gt1 = z1/(1.f+expf(-z1));
  float gt2 = z2/(1.f+expf(-z2)), gt3 = z3/(1.f+expf(-z3));
  float m = fmaxf(fmaxf(gt0, gt1), fmaxf(gt2, gt3));
  m = fmaxf(m, __shfl_xor(m, 16));
  m = fmaxf(m, __shfl_xor(m, 32));
  float e0 = expf(gt0-m), e1 = expf(gt1-m), e2 = expf(gt2-m), e3 = expf(gt3-m);
  float se = e0+e1+e2+e3;
  se += __shfl_xor(se, 16);
  se += __shfl_xor(se, 32);
  float invs = 1.f / se;
  float a0 = e0*invs, a1 = e1*invs, a2 = e2*invs, a3 = e3*invs;

  float4 acc = {0.f,0.f,0.f,0.f};
  {
    float4 v = *(const float4*)(P + (size_t)j4.x*ODIM + 4*p);
    float zx=(q4.x+v.x)*sc4.x+sh4.x, zy=(q4.y+v.y)*sc4.y+sh4.y;
    float zz=(q4.z+v.z)*sc4.z+sh4.z, zw=(q4.w+v.w)*sc4.w+sh4.w;
    acc.x += a0*(zx/(1.f+expf(-zx))); acc.y += a0*(zy/(1.f+expf(-zy)));
    acc.z += a0*(zz/(1.f+expf(-zz))); acc.w += a0*(zw/(1.f+expf(-zw)));
  }
  {
    float4 v = *(const float4*)(P + (size_t)j4.y*ODIM + 4*p);
    float zx=(q4.x+v.x)*sc4.x+sh4.x, zy=(q4.y+v.y)*sc4.y+sh4.y;
    float zz=(q4.z+v.z)*sc4.z+sh4.z, zw=(q4.w+v.w)*sc4.w+sh4.w;
    acc.x += a1*(zx/(1.f+expf(-zx))); acc.y += a1*(zy/(1.f+expf(-zy)));
    acc.z += a1*(zz/(1.f+expf(-zz))); acc.w += a1*(zw/(1.f+expf(-zw)));
  }
  {
    float4 v = *(const float4*)(P + (size_t)j4.z*ODIM + 4*p);
    float zx=(q4.x+v.x)*sc4.x+sh4.x, zy=(q4.y+v.y)*sc4.y+sh4.y;
    float zz=(q4.z+v.z)*sc4.z+sh4.z, zw=(q4.w+v.w)*sc4.w+sh4.w;
    acc.x += a2*(zx/(1.f+expf(-zx))); acc.y += a2*(zy/(1.f+expf(-zy)));
    acc.z += a2*(zz/(1.f+expf(-zz))); acc.w += a2*(zw/(1.f+expf(-zw)));
  }
  {
    float4 v = *(const float4*)(P + (size_t)j4.w*ODIM + 4*p);
    float zx=(q4.x+v.x)*sc4.x+sh4.x, zy=(q4.y+v.y)*sc4.y+sh4.y;
    float zz=(q4.z+v.z)*sc4.z+sh4.z, zw=(q4.w+v.w)*sc4.w+sh4.w;
    acc.x += a3*(zx/(1.f+expf(-zx))); acc.y += a3*(zy/(1.f+expf(-zy)));
    acc.z += a3*(zz/(1.f+expf(-zz))); acc.w += a3*(zw/(1.f+expf(-zw)));
  }
  acc.x += __shfl_xor(acc.x,16); acc.x += __shfl_xor(acc.x,32);
  acc.y += __shfl_xor(acc.y,16); acc.y += __shfl_xor(acc.y,32);
  acc.z += __shfl_xor(acc.z,16); acc.z += __shfl_xor(acc.z,32);
  acc.w += __shfl_xor(acc.w,16); acc.w += __shfl_xor(acc.w,32);
  if (grp == 0)
    *(float4*)(out + (size_t)i*ODIM + 4*p) = acc;
}

extern "C" void kernel_launch(void* const* d_in, const int* in_sizes, int n_in,
                              void* d_out, int out_size, void* d_ws, size_t ws_size,
                              hipStream_t stream) {
  const float* x   = (const float*)d_in[0];
  // d_in[1] = batch (unused: sorted equal-size graphs)
  const float* W1  = (const float*)d_in[2];
  const float* b1  = (const float*)d_in[3];
  const float* g1  = (const float*)d_in[4];
  const float* be1 = (const float*)d_in[5];
  const float* Wg  = (const float*)d_in[6];
  const float* bg  = (const float*)d_in[7];
  const float* gg  = (const float*)d_in[8];
  const float* beg = (const float*)d_in[9];
  float* out = (float*)d_out;

  char* ws = (char*)d_ws;
  int*   idx   = (int*)  (ws);                         // 2 MB
  float* P     = (float*)(ws + 2097152);               // 8 MB
  float* Q     = (float*)(ws + 10485760);              // 8 MB
  float* sq    = (float*)(ws + 18874368);              // 128 KB
  float* pbuf  = (float*)(ws + 19005440);              // 1 MB   [128][<=2048]
  float* gpart = (float*)(ws + 20054016);              // 16 KB  [<=2048][2]
  float* gtbuf = (float*)(ws + 20070400);              // 2 MB   [NEDGE]
  float* scale = (float*)(ws + 22167552);              // 64 f
  float* shift = (float*)(ws + 22167808);              // 64 f
  float* gsc   = (float*)(ws + 22168064);              // 2 f

  pq_kernel<<<NTOT/4, 256, 0, stream>>>(x, W1, b1, P, Q, sq);
  knn_kernel<<<NTOT/KROWS, 256, 0, stream>>>(x, sq, idx);

  // fused cooperative tail: stats1+fin1+stats2+fin2+final (saves ~4 launch gaps)
  void* args[] = {
    (void*)&P, (void*)&Q, (void*)&idx,
    (void*)&g1, (void*)&be1, (void*)&Wg, (void*)&bg, (void*)&gg, (void*)&beg,
    (void*)&pbuf, (void*)&gpart, (void*)&gtbuf,
    (void*)&scale, (void*)&shift, (void*)&gsc, (void*)&out
  };
  hipError_t cerr = hipLaunchCooperativeKernel(
      reinterpret_cast<void*>(fused_kernel), dim3(NBLKF), dim3(256),
      args, 0, stream);
  if (cerr != hipSuccess) {
    // fallback: r9-verified 5-kernel path
    stats1_kernel<<<NBLK_E, 256, 0, stream>>>(P, Q, idx, pbuf);
    fin1_kernel<<<ODIM, 64, 0, stream>>>(pbuf, g1, be1, scale, shift);
    stats2_kernel<<<NBLK_E, 256, 0, stream>>>(P, Q, idx, scale, shift, Wg, bg, gtbuf, gpart);
    fin2_kernel<<<1, 256, 0, stream>>>(gpart, gg, beg, gsc);
    final_kernel<<<NTOT/4, 256, 0, stream>>>(P, Q, idx, scale, shift, gtbuf, gsc, out);
  }
}